// Round 1
// baseline (338.209 us; speedup 1.0000x reference)
//
#include <hip/hip_runtime.h>
#include <math.h>

#define HID 64
#define T_OUT 4
#define IN_DIM 26
#define NF 4
#define D0 8
#define LPE_OUT 24

template<int R>
__device__ __forceinline__ void gather_level(const float* __restrict__ g,
                                             float u, float v,
                                             float& e0, float& e1) {
    const float scale = (float)(R - 1);
    float fu = u * scale, fv = v * scale;
    int i0 = (int)floorf(fu);
    int j0 = (int)floorf(fv);
    i0 = i0 < 0 ? 0 : (i0 > R - 2 ? R - 2 : i0);
    j0 = j0 < 0 ? 0 : (j0 > R - 2 ? R - 2 : j0);
    float lu = fu - (float)i0;
    float lv = fv - (float)j0;
    const float2* gg = (const float2*)g;
    int base = i0 + j0 * R;
    float2 f00 = gg[base];
    float2 f10 = gg[base + 1];
    float2 f01 = gg[base + R];
    float2 f11 = gg[base + R + 1];
    float omu = 1.f - lu, omv = 1.f - lv;
    float w00 = omu * omv, w10 = lu * omv, w01 = omu * lv, w11 = lu * lv;
    e0 += f00.x * w00 + f10.x * w10 + f01.x * w01 + f11.x * w11;
    e1 += f00.y * w00 + f10.y * w10 + f01.y * w01 + f11.y * w11;
}

__global__ __launch_bounds__(256)
void colornet_kernel(const float2* __restrict__ coords,
                     const float* __restrict__ g0, const float* __restrict__ g1,
                     const float* __restrict__ g2, const float* __restrict__ g3,
                     const float* __restrict__ g4, const float* __restrict__ g5,
                     const float* __restrict__ g6, const float* __restrict__ g7,
                     const float* __restrict__ lpe,
                     const float* __restrict__ w0, const float* __restrict__ b0,
                     const float* __restrict__ w1, const float* __restrict__ b1,
                     const float* __restrict__ w2, const float* __restrict__ b2,
                     float4* __restrict__ out, int B)
{
    int idx = blockIdx.x * blockDim.x + threadIdx.x;
    if (idx >= B) return;

    float2 c = coords[idx];
    float u = fminf(fmaxf(c.x, 0.f), 1.f - 1e-6f);
    float v = fminf(fmaxf(c.y, 0.f), 1.f - 1e-6f);

    // ---- multiresolution bilinear encoding (FD=2) ----
    float e0 = 0.f, e1 = 0.f;
    gather_level<16>(g0, u, v, e0, e1);
    gather_level<32>(g1, u, v, e0, e1);
    gather_level<64>(g2, u, v, e0, e1);
    gather_level<128>(g3, u, v, e0, e1);
    gather_level<256>(g4, u, v, e0, e1);
    gather_level<512>(g5, u, v, e0, e1);
    gather_level<1024>(g6, u, v, e0, e1);
    gather_level<2048>(g7, u, v, e0, e1);

    // ---- LPE gather (24 channels) + lu/lv for PE ----
    float coeff[LPE_OUT];
    float lu_pe, lv_pe;
    {
        float fu = u * 128.f, fv = v * 128.f;
        int i0 = (int)floorf(fu);
        int j0 = (int)floorf(fv);
        i0 = i0 < 0 ? 0 : (i0 > 127 ? 127 : i0);
        j0 = j0 < 0 ? 0 : (j0 > 127 ? 127 : j0);
        lu_pe = fu - (float)i0;
        lv_pe = fv - (float)j0;
        int base = (i0 + j0 * 129) * LPE_OUT;
        const float4* p00 = (const float4*)(lpe + base);
        const float4* p10 = (const float4*)(lpe + base + LPE_OUT);
        const float4* p01 = (const float4*)(lpe + base + 129 * LPE_OUT);
        const float4* p11 = (const float4*)(lpe + base + 130 * LPE_OUT);
        float omu = 1.f - lu_pe, omv = 1.f - lv_pe;
        float w00 = omu * omv, w10 = lu_pe * omv, w01 = omu * lv_pe, w11 = lu_pe * lv_pe;
#pragma unroll
        for (int q = 0; q < 6; ++q) {
            float4 a = p00[q], bq = p10[q], cq = p01[q], dq = p11[q];
            coeff[4 * q + 0] = a.x * w00 + bq.x * w10 + cq.x * w01 + dq.x * w11;
            coeff[4 * q + 1] = a.y * w00 + bq.y * w10 + cq.y * w01 + dq.y * w11;
            coeff[4 * q + 2] = a.z * w00 + bq.z * w10 + cq.z * w01 + dq.z * w11;
            coeff[4 * q + 3] = a.w * w00 + bq.w * w10 + cq.w * w01 + dq.w * w11;
        }
    }

    // ---- positional encoding: freqs = 2^k * 2*pi, k=0..3 ----
    float pe[4 * NF];
#pragma unroll
    for (int kf = 0; kf < NF; ++kf) {
        const float fr = 6.28318530717958647692f * (float)(1 << kf);
        float au = lu_pe * fr;
        float av = lv_pe * fr;
        pe[kf]          = __cosf(au);
        pe[NF + kf]     = __sinf(au);
        pe[2 * NF + kf] = __cosf(av);
        pe[3 * NF + kf] = __sinf(av);
    }

    // ---- feature vector: [enc(2), base(8), gate*pe(16)] ----
    float feat[IN_DIM];
    feat[0] = e0;
    feat[1] = e1;
#pragma unroll
    for (int q = 0; q < D0; ++q) feat[2 + q] = coeff[q];
#pragma unroll
    for (int q = 0; q < 4 * NF; ++q) feat[2 + D0 + q] = coeff[D0 + q] * pe[q];

    // ---- layer 0: 26 -> 64, relu ----
    float h0[HID];
#pragma unroll
    for (int k = 0; k < HID; ++k) h0[k] = b0[k];
#pragma unroll
    for (int j = 0; j < IN_DIM; ++j) {
        float f = feat[j];
#pragma unroll
        for (int k = 0; k < HID; ++k) h0[k] = fmaf(f, w0[j * HID + k], h0[k]);
    }
#pragma unroll
    for (int k = 0; k < HID; ++k) h0[k] = fmaxf(h0[k], 0.f);

    // ---- layer 1: 64 -> 64, relu ----
    float h1[HID];
#pragma unroll
    for (int k = 0; k < HID; ++k) h1[k] = b1[k];
#pragma unroll
    for (int j = 0; j < HID; ++j) {
        float f = h0[j];
#pragma unroll
        for (int k = 0; k < HID; ++k) h1[k] = fmaf(f, w1[j * HID + k], h1[k]);
    }
#pragma unroll
    for (int k = 0; k < HID; ++k) h1[k] = fmaxf(h1[k], 0.f);

    // ---- layer 2: 64 -> 4, sigmoid ----
    float o[T_OUT];
#pragma unroll
    for (int t = 0; t < T_OUT; ++t) o[t] = b2[t];
#pragma unroll
    for (int j = 0; j < HID; ++j) {
        float f = h1[j];
#pragma unroll
        for (int t = 0; t < T_OUT; ++t) o[t] = fmaf(f, w2[j * T_OUT + t], o[t]);
    }

    float4 r;
    r.x = 1.f / (1.f + __expf(-o[0]));
    r.y = 1.f / (1.f + __expf(-o[1]));
    r.z = 1.f / (1.f + __expf(-o[2]));
    r.w = 1.f / (1.f + __expf(-o[3]));
    out[idx] = r;
}

extern "C" void kernel_launch(void* const* d_in, const int* in_sizes, int n_in,
                              void* d_out, int out_size, void* d_ws, size_t ws_size,
                              hipStream_t stream) {
    const float2* coords = (const float2*)d_in[0];
    const float* g0 = (const float*)d_in[1];
    const float* g1 = (const float*)d_in[2];
    const float* g2 = (const float*)d_in[3];
    const float* g3 = (const float*)d_in[4];
    const float* g4 = (const float*)d_in[5];
    const float* g5 = (const float*)d_in[6];
    const float* g6 = (const float*)d_in[7];
    const float* g7 = (const float*)d_in[8];
    const float* lpe = (const float*)d_in[9];
    const float* w0 = (const float*)d_in[10];
    const float* b0 = (const float*)d_in[11];
    const float* w1 = (const float*)d_in[12];
    const float* b1 = (const float*)d_in[13];
    const float* w2 = (const float*)d_in[14];
    const float* b2 = (const float*)d_in[15];
    float4* out = (float4*)d_out;

    int B = in_sizes[0] / 2;
    int block = 256;
    int grid = (B + block - 1) / block;
    colornet_kernel<<<grid, block, 0, stream>>>(coords, g0, g1, g2, g3, g4, g5, g6, g7,
                                                lpe, w0, b0, w1, b1, w2, b2, out, B);
}

// Round 2
// 299.842 us; speedup vs baseline: 1.1280x; 1.1280x over previous
//
#include <hip/hip_runtime.h>
#include <math.h>

#define HID 64
#define T_OUT 4
#define IN_DIM 26
#define NF 4
#define D0 8
#define LPE_OUT 24

template<int R>
__device__ __forceinline__ void gather_level(const float* __restrict__ g,
                                             float u, float v,
                                             float& e0, float& e1) {
    const float scale = (float)(R - 1);
    float fu = u * scale, fv = v * scale;
    int i0 = (int)floorf(fu);
    int j0 = (int)floorf(fv);
    i0 = i0 < 0 ? 0 : (i0 > R - 2 ? R - 2 : i0);
    j0 = j0 < 0 ? 0 : (j0 > R - 2 ? R - 2 : j0);
    float lu = fu - (float)i0;
    float lv = fv - (float)j0;
    const float2* gg = (const float2*)g;
    int base = i0 + j0 * R;
    float2 f00 = gg[base];
    float2 f10 = gg[base + 1];
    float2 f01 = gg[base + R];
    float2 f11 = gg[base + R + 1];
    float omu = 1.f - lu, omv = 1.f - lv;
    float w00 = omu * omv, w10 = lu * omv, w01 = omu * lv, w11 = lu * lv;
    e0 += f00.x * w00 + f10.x * w10 + f01.x * w01 + f11.x * w11;
    e1 += f00.y * w00 + f10.y * w10 + f01.y * w01 + f11.y * w11;
}

__global__ __launch_bounds__(256, 4)
void colornet_kernel(const float2* __restrict__ coords,
                     const float* __restrict__ g0, const float* __restrict__ g1,
                     const float* __restrict__ g2, const float* __restrict__ g3,
                     const float* __restrict__ g4, const float* __restrict__ g5,
                     const float* __restrict__ g6, const float* __restrict__ g7,
                     const float* __restrict__ lpe,
                     const float* __restrict__ w0, const float* __restrict__ b0,
                     const float* __restrict__ w1, const float* __restrict__ b1,
                     const float* __restrict__ w2, const float* __restrict__ b2,
                     float4* __restrict__ out, int B)
{
    int idx = blockIdx.x * blockDim.x + threadIdx.x;
    if (idx >= B) return;

    float2 c = coords[idx];
    float u = fminf(fmaxf(c.x, 0.f), 1.f - 1e-6f);
    float v = fminf(fmaxf(c.y, 0.f), 1.f - 1e-6f);

    // ---- multiresolution bilinear encoding (FD=2) ----
    float e0 = 0.f, e1 = 0.f;
    gather_level<16>(g0, u, v, e0, e1);
    gather_level<32>(g1, u, v, e0, e1);
    gather_level<64>(g2, u, v, e0, e1);
    gather_level<128>(g3, u, v, e0, e1);
    gather_level<256>(g4, u, v, e0, e1);
    gather_level<512>(g5, u, v, e0, e1);
    gather_level<1024>(g6, u, v, e0, e1);
    gather_level<2048>(g7, u, v, e0, e1);

    // ---- LPE gather (24 channels) + lu/lv for PE ----
    float coeff[LPE_OUT];
    float lu_pe, lv_pe;
    {
        float fu = u * 128.f, fv = v * 128.f;
        int i0 = (int)floorf(fu);
        int j0 = (int)floorf(fv);
        i0 = i0 < 0 ? 0 : (i0 > 127 ? 127 : i0);
        j0 = j0 < 0 ? 0 : (j0 > 127 ? 127 : j0);
        lu_pe = fu - (float)i0;
        lv_pe = fv - (float)j0;
        int base = (i0 + j0 * 129) * LPE_OUT;
        const float4* p00 = (const float4*)(lpe + base);
        const float4* p10 = (const float4*)(lpe + base + LPE_OUT);
        const float4* p01 = (const float4*)(lpe + base + 129 * LPE_OUT);
        const float4* p11 = (const float4*)(lpe + base + 130 * LPE_OUT);
        float omu = 1.f - lu_pe, omv = 1.f - lv_pe;
        float w00 = omu * omv, w10 = lu_pe * omv, w01 = omu * lv_pe, w11 = lu_pe * lv_pe;
#pragma unroll
        for (int q = 0; q < 6; ++q) {
            float4 a = p00[q], bq = p10[q], cq = p01[q], dq = p11[q];
            coeff[4 * q + 0] = a.x * w00 + bq.x * w10 + cq.x * w01 + dq.x * w11;
            coeff[4 * q + 1] = a.y * w00 + bq.y * w10 + cq.y * w01 + dq.y * w11;
            coeff[4 * q + 2] = a.z * w00 + bq.z * w10 + cq.z * w01 + dq.z * w11;
            coeff[4 * q + 3] = a.w * w00 + bq.w * w10 + cq.w * w01 + dq.w * w11;
        }
    }

    // ---- positional encoding: freqs = 2^k * 2*pi, k=0..3 ----
    float pe[4 * NF];
#pragma unroll
    for (int kf = 0; kf < NF; ++kf) {
        const float fr = 6.28318530717958647692f * (float)(1 << kf);
        float au = lu_pe * fr;
        float av = lv_pe * fr;
        pe[kf]          = __cosf(au);
        pe[NF + kf]     = __sinf(au);
        pe[2 * NF + kf] = __cosf(av);
        pe[3 * NF + kf] = __sinf(av);
    }

    // ---- feature vector: [enc(2), base(8), gate*pe(16)] ----
    float feat[IN_DIM];
    feat[0] = e0;
    feat[1] = e1;
#pragma unroll
    for (int q = 0; q < D0; ++q) feat[2 + q] = coeff[q];
#pragma unroll
    for (int q = 0; q < 4 * NF; ++q) feat[2 + D0 + q] = coeff[D0 + q] * pe[q];

    // ---- layer 0: 26 -> 64, relu ----
    float h0[HID];
#pragma unroll
    for (int k = 0; k < HID; ++k) h0[k] = b0[k];
#pragma unroll
    for (int j = 0; j < IN_DIM; ++j) {
        float f = feat[j];
#pragma unroll
        for (int k = 0; k < HID; ++k) h0[k] = fmaf(f, w0[j * HID + k], h0[k]);
    }
#pragma unroll
    for (int k = 0; k < HID; ++k) h0[k] = fmaxf(h0[k], 0.f);

    // ---- layers 1+2 fused: 64 -> 64 (relu) -> 4, half-split to cap live regs ----
    float o[T_OUT];
#pragma unroll
    for (int t = 0; t < T_OUT; ++t) o[t] = b2[t];

#pragma unroll
    for (int h = 0; h < 2; ++h) {
        float acc[32];
#pragma unroll
        for (int k = 0; k < 32; ++k) acc[k] = b1[h * 32 + k];
#pragma unroll
        for (int j = 0; j < HID; ++j) {
            float f = h0[j];
#pragma unroll
            for (int k = 0; k < 32; ++k)
                acc[k] = fmaf(f, w1[j * HID + h * 32 + k], acc[k]);
        }
#pragma unroll
        for (int k = 0; k < 32; ++k) {
            float hv = fmaxf(acc[k], 0.f);
#pragma unroll
            for (int t = 0; t < T_OUT; ++t)
                o[t] = fmaf(hv, w2[(h * 32 + k) * T_OUT + t], o[t]);
        }
    }

    float4 r;
    r.x = 1.f / (1.f + __expf(-o[0]));
    r.y = 1.f / (1.f + __expf(-o[1]));
    r.z = 1.f / (1.f + __expf(-o[2]));
    r.w = 1.f / (1.f + __expf(-o[3]));
    out[idx] = r;
}

extern "C" void kernel_launch(void* const* d_in, const int* in_sizes, int n_in,
                              void* d_out, int out_size, void* d_ws, size_t ws_size,
                              hipStream_t stream) {
    const float2* coords = (const float2*)d_in[0];
    const float* g0 = (const float*)d_in[1];
    const float* g1 = (const float*)d_in[2];
    const float* g2 = (const float*)d_in[3];
    const float* g3 = (const float*)d_in[4];
    const float* g4 = (const float*)d_in[5];
    const float* g5 = (const float*)d_in[6];
    const float* g6 = (const float*)d_in[7];
    const float* g7 = (const float*)d_in[8];
    const float* lpe = (const float*)d_in[9];
    const float* w0 = (const float*)d_in[10];
    const float* b0 = (const float*)d_in[11];
    const float* w1 = (const float*)d_in[12];
    const float* b1 = (const float*)d_in[13];
    const float* w2 = (const float*)d_in[14];
    const float* b2 = (const float*)d_in[15];
    float4* out = (float4*)d_out;

    int B = in_sizes[0] / 2;
    int block = 256;
    int grid = (B + block - 1) / block;
    colornet_kernel<<<grid, block, 0, stream>>>(coords, g0, g1, g2, g3, g4, g5, g6, g7,
                                                lpe, w0, b0, w1, b1, w2, b2, out, B);
}

// Round 3
// 198.169 us; speedup vs baseline: 1.7067x; 1.5131x over previous
//
#include <hip/hip_runtime.h>
#include <math.h>

typedef short bf16x8 __attribute__((ext_vector_type(8)));
typedef float f32x16 __attribute__((ext_vector_type(16)));

#define HID 64
#define NF 4
#define D0 8
#define LPE_OUT 24

// ---------- bf16 helpers (manual RNE pack; safe, ~6 VALU) ----------
__device__ __forceinline__ unsigned f2bf(float x) {
    unsigned u = __float_as_uint(x);
    u = u + 0x7fffu + ((u >> 16) & 1u);
    return u >> 16;
}
__device__ __forceinline__ unsigned pkbf(float a, float b) {
    return f2bf(a) | (f2bf(b) << 16);
}

// ---------- weight prep: fp32 -> bf16 A-fragments in d_ws ----------
// ws layout (bytes):
//   [0,4096)      A0 frags : 4 tiles (m*2+ks) x 64 lanes x 8 bf16
//   [4096,12288)  A1 frags : 8 tiles (m*4+ks) x 64 x 8
//   [12288,16384) A2 frags : 4 tiles (ks)     x 64 x 8
//   [16384,16640) b0c: (m*2+q5)*16 + r  f32   (C-layout bias)
//   [16640,16896) b1c: same
__global__ void prep_kernel(const float* __restrict__ w0, const float* __restrict__ b0,
                            const float* __restrict__ w1, const float* __restrict__ b1,
                            const float* __restrict__ w2, float* __restrict__ ws)
{
    int t = threadIdx.x;
    unsigned short* a0 = (unsigned short*)ws;
    unsigned short* a1 = a0 + 2048;
    unsigned short* a2 = a1 + 4096;
    float* b0c = (float*)(a2 + 2048);
    float* b1c = b0c + 64;

    // A0 = W0^T : A(row=h, k=feat) = w0[k*64+row], zero-pad k>=26
    for (int e = t; e < 2048; e += 256) {
        int tile = e >> 9, lane = (e >> 3) & 63, j = e & 7;
        int m = tile >> 1, ks = tile & 1;
        int row = m * 32 + (lane & 31);
        int k = ks * 16 + (lane >> 5) * 8 + j;
        float v = (k < 26) ? w0[k * 64 + row] : 0.f;
        a0[e] = (unsigned short)f2bf(v);
    }
    // A1 = W1^T : A(row=h_out, k=h_in) = w1[k*64+row]
    for (int e = t; e < 4096; e += 256) {
        int tile = e >> 9, lane = (e >> 3) & 63, j = e & 7;
        int m = tile >> 2, ks = tile & 3;
        int row = m * 32 + (lane & 31);
        int k = ks * 16 + (lane >> 5) * 8 + j;
        a1[e] = (unsigned short)f2bf(w1[k * 64 + row]);
    }
    // A2 = W2^T : A(row=t, k=h_in) = w2[k*4+row], rows 4..31 zero
    for (int e = t; e < 2048; e += 256) {
        int ks = e >> 9, lane = (e >> 3) & 63, j = e & 7;
        int row = lane & 31;
        int k = ks * 16 + (lane >> 5) * 8 + j;
        float v = (row < 4) ? w2[k * 4 + row] : 0.f;
        a2[e] = (unsigned short)f2bf(v);
    }
    // bias in C-fragment order: row = 32m + (r&3) + 8*(r>>2) + 4*q5
    if (t < 64) {
        int m = t >> 5, q5 = (t >> 4) & 1, r = t & 15;
        int row = (r & 3) + 8 * (r >> 2) + 4 * q5;
        b0c[(m * 2 + q5) * 16 + r] = b0[m * 32 + row];
        b1c[(m * 2 + q5) * 16 + r] = b1[m * 32 + row];
    }
}

// ---------- gather helper (unchanged, known-correct) ----------
template<int R>
__device__ __forceinline__ void gather_level(const float* __restrict__ g,
                                             float u, float v,
                                             float& e0, float& e1) {
    const float scale = (float)(R - 1);
    float fu = u * scale, fv = v * scale;
    int i0 = (int)floorf(fu);
    int j0 = (int)floorf(fv);
    i0 = i0 < 0 ? 0 : (i0 > R - 2 ? R - 2 : i0);
    j0 = j0 < 0 ? 0 : (j0 > R - 2 ? R - 2 : j0);
    float lu = fu - (float)i0;
    float lv = fv - (float)j0;
    const float2* gg = (const float2*)g;
    int base = i0 + j0 * R;
    float2 f00 = gg[base];
    float2 f10 = gg[base + 1];
    float2 f01 = gg[base + R];
    float2 f11 = gg[base + R + 1];
    float omu = 1.f - lu, omv = 1.f - lv;
    float w00 = omu * omv, w10 = lu * omv, w01 = omu * lv, w11 = lu * lv;
    e0 += f00.x * w00 + f10.x * w10 + f01.x * w01 + f11.x * w11;
    e1 += f00.y * w00 + f10.y * w10 + f01.y * w01 + f11.y * w11;
}

// ---------- main fused kernel: gather (per-lane) + MFMA MLP (per-wave) ----------
__global__ __launch_bounds__(256, 2)
void colornet_mfma(const float2* __restrict__ coords,
                   const float* __restrict__ g0, const float* __restrict__ g1,
                   const float* __restrict__ g2, const float* __restrict__ g3,
                   const float* __restrict__ g4, const float* __restrict__ g5,
                   const float* __restrict__ g6, const float* __restrict__ g7,
                   const float* __restrict__ lpe,
                   const float* __restrict__ ws,
                   const float* __restrict__ b2,
                   float4* __restrict__ out)
{
    // per-wave LDS: 12 chunks of 64x16B ([k8][point] bf16 fragment layout)
    // chunks 0..3: feat (k=0..31) ; 4..11: h0 (k=0..63) ; h1 reuses 0..7
    __shared__ int4 smem[4 * 12 * 64];

    const int lane = threadIdx.x & 63;
    const int wave = threadIdx.x >> 6;
    const int q5 = lane >> 5;
    const int l31 = lane & 31;
    const int base_pt = blockIdx.x * 256 + wave * 64;
    const int point = base_pt + lane;

    // ================= gather phase (per lane, one point) =================
    float2 c = coords[point];
    float u = fminf(fmaxf(c.x, 0.f), 1.f - 1e-6f);
    float v = fminf(fmaxf(c.y, 0.f), 1.f - 1e-6f);

    float e0 = 0.f, e1 = 0.f;
    gather_level<16>(g0, u, v, e0, e1);
    gather_level<32>(g1, u, v, e0, e1);
    gather_level<64>(g2, u, v, e0, e1);
    gather_level<128>(g3, u, v, e0, e1);
    gather_level<256>(g4, u, v, e0, e1);
    gather_level<512>(g5, u, v, e0, e1);
    gather_level<1024>(g6, u, v, e0, e1);
    gather_level<2048>(g7, u, v, e0, e1);

    float coeff[LPE_OUT];
    float lu_pe, lv_pe;
    {
        float fu = u * 128.f, fv = v * 128.f;
        int i0 = (int)floorf(fu);
        int j0 = (int)floorf(fv);
        i0 = i0 < 0 ? 0 : (i0 > 127 ? 127 : i0);
        j0 = j0 < 0 ? 0 : (j0 > 127 ? 127 : j0);
        lu_pe = fu - (float)i0;
        lv_pe = fv - (float)j0;
        int base = (i0 + j0 * 129) * LPE_OUT;
        const float4* p00 = (const float4*)(lpe + base);
        const float4* p10 = (const float4*)(lpe + base + LPE_OUT);
        const float4* p01 = (const float4*)(lpe + base + 129 * LPE_OUT);
        const float4* p11 = (const float4*)(lpe + base + 130 * LPE_OUT);
        float omu = 1.f - lu_pe, omv = 1.f - lv_pe;
        float w00 = omu * omv, w10 = lu_pe * omv, w01 = omu * lv_pe, w11 = lu_pe * lv_pe;
#pragma unroll
        for (int q = 0; q < 6; ++q) {
            float4 a = p00[q], bq = p10[q], cq = p01[q], dq = p11[q];
            coeff[4 * q + 0] = a.x * w00 + bq.x * w10 + cq.x * w01 + dq.x * w11;
            coeff[4 * q + 1] = a.y * w00 + bq.y * w10 + cq.y * w01 + dq.y * w11;
            coeff[4 * q + 2] = a.z * w00 + bq.z * w10 + cq.z * w01 + dq.z * w11;
            coeff[4 * q + 3] = a.w * w00 + bq.w * w10 + cq.w * w01 + dq.w * w11;
        }
    }

    float pe[4 * NF];
#pragma unroll
    for (int kf = 0; kf < NF; ++kf) {
        const float fr = 6.28318530717958647692f * (float)(1 << kf);
        float au = lu_pe * fr;
        float av = lv_pe * fr;
        pe[kf]          = __cosf(au);
        pe[NF + kf]     = __sinf(au);
        pe[2 * NF + kf] = __cosf(av);
        pe[3 * NF + kf] = __sinf(av);
    }

    float feat[32];
    feat[0] = e0;
    feat[1] = e1;
#pragma unroll
    for (int q = 0; q < D0; ++q) feat[2 + q] = coeff[q];
#pragma unroll
    for (int q = 0; q < 4 * NF; ++q) feat[2 + D0 + q] = coeff[D0 + q] * pe[q];
#pragma unroll
    for (int q = 26; q < 32; ++q) feat[q] = 0.f;

    // ============ stage features to LDS [k8][point] as bf16 ============
    unsigned fd[16];
#pragma unroll
    for (int i = 0; i < 16; ++i) fd[i] = pkbf(feat[2 * i], feat[2 * i + 1]);
#pragma unroll
    for (int cc = 0; cc < 4; ++cc)
        smem[(wave * 12 + cc) * 64 + lane] =
            make_int4((int)fd[4 * cc], (int)fd[4 * cc + 1], (int)fd[4 * cc + 2], (int)fd[4 * cc + 3]);

    const bf16x8* A0 = (const bf16x8*)ws;
    const bf16x8* A1 = (const bf16x8*)((const char*)ws + 4096);
    const bf16x8* A2 = (const bf16x8*)((const char*)ws + 12288);
    const float4* b0c = (const float4*)((const char*)ws + 16384);
    const float4* b1c = (const float4*)((const char*)ws + 16640);
    uint2* sm2 = (uint2*)smem;

    // ================= layer 0: D0[h=64][p=64] = W0^T x feat =================
    f32x16 acc[2][2];
#pragma unroll
    for (int m = 0; m < 2; ++m) {
#pragma unroll
        for (int cc = 0; cc < 4; ++cc) {
            float4 bq = b0c[(m * 2 + q5) * 4 + cc];
#pragma unroll
            for (int n = 0; n < 2; ++n) {
                acc[m][n][4 * cc + 0] = bq.x;
                acc[m][n][4 * cc + 1] = bq.y;
                acc[m][n][4 * cc + 2] = bq.z;
                acc[m][n][4 * cc + 3] = bq.w;
            }
        }
    }
#pragma unroll
    for (int ks = 0; ks < 2; ++ks) {
        bf16x8 bf0 = *(const bf16x8*)&smem[(wave * 12 + 2 * ks + q5) * 64 + l31];
        bf16x8 bf1 = *(const bf16x8*)&smem[(wave * 12 + 2 * ks + q5) * 64 + 32 + l31];
        bf16x8 af0 = A0[(0 * 2 + ks) * 64 + lane];
        bf16x8 af1 = A0[(1 * 2 + ks) * 64 + lane];
        acc[0][0] = __builtin_amdgcn_mfma_f32_32x32x16_bf16(af0, bf0, acc[0][0], 0, 0, 0);
        acc[0][1] = __builtin_amdgcn_mfma_f32_32x32x16_bf16(af0, bf1, acc[0][1], 0, 0, 0);
        acc[1][0] = __builtin_amdgcn_mfma_f32_32x32x16_bf16(af1, bf0, acc[1][0], 0, 0, 0);
        acc[1][1] = __builtin_amdgcn_mfma_f32_32x32x16_bf16(af1, bf1, acc[1][1], 0, 0, 0);
    }

    // relu -> bf16 -> stage h0 to chunks 4..11 ([k8][point])
#pragma unroll
    for (int m = 0; m < 2; ++m)
#pragma unroll
        for (int n = 0; n < 2; ++n) {
            unsigned d[8];
#pragma unroll
            for (int s = 0; s < 8; ++s)
                d[s] = pkbf(fmaxf(acc[m][n][2 * s], 0.f), fmaxf(acc[m][n][2 * s + 1], 0.f));
#pragma unroll
            for (int Q = 0; Q < 4; ++Q)
                sm2[((wave * 12 + 4 + 4 * m + Q) * 64 + 32 * n + l31) * 2 + q5] =
                    make_uint2(d[2 * Q], d[2 * Q + 1]);
        }

    // ================= layer 1: D1[h=64][p=64] = W1^T x h0 =================
    f32x16 acc1[2][2];
#pragma unroll
    for (int m = 0; m < 2; ++m) {
#pragma unroll
        for (int cc = 0; cc < 4; ++cc) {
            float4 bq = b1c[(m * 2 + q5) * 4 + cc];
#pragma unroll
            for (int n = 0; n < 2; ++n) {
                acc1[m][n][4 * cc + 0] = bq.x;
                acc1[m][n][4 * cc + 1] = bq.y;
                acc1[m][n][4 * cc + 2] = bq.z;
                acc1[m][n][4 * cc + 3] = bq.w;
            }
        }
    }
#pragma unroll
    for (int ks = 0; ks < 4; ++ks) {
        bf16x8 bf0 = *(const bf16x8*)&smem[(wave * 12 + 4 + 2 * ks + q5) * 64 + l31];
        bf16x8 bf1 = *(const bf16x8*)&smem[(wave * 12 + 4 + 2 * ks + q5) * 64 + 32 + l31];
        bf16x8 af0 = A1[(0 * 4 + ks) * 64 + lane];
        bf16x8 af1 = A1[(1 * 4 + ks) * 64 + lane];
        acc1[0][0] = __builtin_amdgcn_mfma_f32_32x32x16_bf16(af0, bf0, acc1[0][0], 0, 0, 0);
        acc1[0][1] = __builtin_amdgcn_mfma_f32_32x32x16_bf16(af0, bf1, acc1[0][1], 0, 0, 0);
        acc1[1][0] = __builtin_amdgcn_mfma_f32_32x32x16_bf16(af1, bf0, acc1[1][0], 0, 0, 0);
        acc1[1][1] = __builtin_amdgcn_mfma_f32_32x32x16_bf16(af1, bf1, acc1[1][1], 0, 0, 0);
    }

    // relu -> bf16 -> stage h1 to chunks 0..7
#pragma unroll
    for (int m = 0; m < 2; ++m)
#pragma unroll
        for (int n = 0; n < 2; ++n) {
            unsigned d[8];
#pragma unroll
            for (int s = 0; s < 8; ++s)
                d[s] = pkbf(fmaxf(acc1[m][n][2 * s], 0.f), fmaxf(acc1[m][n][2 * s + 1], 0.f));
#pragma unroll
            for (int Q = 0; Q < 4; ++Q)
                sm2[((wave * 12 + 4 * m + Q) * 64 + 32 * n + l31) * 2 + q5] =
                    make_uint2(d[2 * Q], d[2 * Q + 1]);
        }

    // ================= layer 2: D2[t=4(pad32)][p=64] = W2^T x h1 =================
    f32x16 acc2[2];
#pragma unroll
    for (int n = 0; n < 2; ++n) {
#pragma unroll
        for (int r = 0; r < 16; ++r) acc2[n][r] = (r < 4) ? b2[r] : 0.f;
    }
#pragma unroll
    for (int ks = 0; ks < 4; ++ks) {
        bf16x8 bf0 = *(const bf16x8*)&smem[(wave * 12 + 2 * ks + q5) * 64 + l31];
        bf16x8 bf1 = *(const bf16x8*)&smem[(wave * 12 + 2 * ks + q5) * 64 + 32 + l31];
        bf16x8 af = A2[ks * 64 + lane];
        acc2[0] = __builtin_amdgcn_mfma_f32_32x32x16_bf16(af, bf0, acc2[0], 0, 0, 0);
        acc2[1] = __builtin_amdgcn_mfma_f32_32x32x16_bf16(af, bf1, acc2[1], 0, 0, 0);
    }

    // sigmoid + store: lanes 0..31 hold rows t=0..3 (q5==0)
    if (lane < 32) {
#pragma unroll
        for (int n = 0; n < 2; ++n) {
            float4 o;
            o.x = 1.f / (1.f + __expf(-acc2[n][0]));
            o.y = 1.f / (1.f + __expf(-acc2[n][1]));
            o.z = 1.f / (1.f + __expf(-acc2[n][2]));
            o.w = 1.f / (1.f + __expf(-acc2[n][3]));
            out[base_pt + 32 * n + lane] = o;
        }
    }
}

extern "C" void kernel_launch(void* const* d_in, const int* in_sizes, int n_in,
                              void* d_out, int out_size, void* d_ws, size_t ws_size,
                              hipStream_t stream) {
    const float2* coords = (const float2*)d_in[0];
    const float* g0 = (const float*)d_in[1];
    const float* g1 = (const float*)d_in[2];
    const float* g2 = (const float*)d_in[3];
    const float* g3 = (const float*)d_in[4];
    const float* g4 = (const float*)d_in[5];
    const float* g5 = (const float*)d_in[6];
    const float* g6 = (const float*)d_in[7];
    const float* g7 = (const float*)d_in[8];
    const float* lpe = (const float*)d_in[9];
    const float* w0 = (const float*)d_in[10];
    const float* b0 = (const float*)d_in[11];
    const float* w1 = (const float*)d_in[12];
    const float* b1 = (const float*)d_in[13];
    const float* w2 = (const float*)d_in[14];
    const float* b2 = (const float*)d_in[15];
    float4* out = (float4*)d_out;

    int B = in_sizes[0] / 2;

    prep_kernel<<<1, 256, 0, stream>>>(w0, b0, w1, b1, w2, (float*)d_ws);

    int grid = B / 256;   // B = 1048576 -> 4096 blocks, exact
    colornet_mfma<<<grid, 256, 0, stream>>>(coords, g0, g1, g2, g3, g4, g5, g6, g7,
                                            lpe, (const float*)d_ws, b2, out);
}

// Round 4
// 195.166 us; speedup vs baseline: 1.7329x; 1.0154x over previous
//
#include <hip/hip_runtime.h>
#include <math.h>

typedef short bf16x8 __attribute__((ext_vector_type(8)));
typedef float f32x16 __attribute__((ext_vector_type(16)));
typedef float f32x4 __attribute__((ext_vector_type(4)));
typedef unsigned u32x4 __attribute__((ext_vector_type(4)));

#define NF 4
#define D0 8
#define LPE_OUT 24

// ---------- bf16 helpers (manual RNE pack) ----------
__device__ __forceinline__ unsigned f2bf(float x) {
    unsigned u = __float_as_uint(x);
    u = u + 0x7fffu + ((u >> 16) & 1u);
    return u >> 16;
}
__device__ __forceinline__ unsigned pkbf(float a, float b) {
    return f2bf(a) | (f2bf(b) << 16);
}
__device__ __forceinline__ bf16x8 mkfrag(unsigned w0, unsigned w1, unsigned w2, unsigned w3) {
    u32x4 u = { w0, w1, w2, w3 };
    return __builtin_bit_cast(bf16x8, u);
}

// ---------- weight prep: fp32 -> bf16 A-fragments in d_ws (UNCHANGED, R3-verified) ----------
// ws layout (bytes):
//   [0,4096)      A0 frags : 4 tiles (m*2+ks) x 64 lanes x 8 bf16
//   [4096,12288)  A1 frags : 8 tiles (m*4+ks) x 64 x 8
//   [12288,16384) A2 frags : 4 tiles (ks)     x 64 x 8
//   [16384,16640) b0c: (m*2+q5)*16 + r  f32   (C-layout bias)
//   [16640,16896) b1c: same
__global__ void prep_kernel(const float* __restrict__ w0, const float* __restrict__ b0,
                            const float* __restrict__ w1, const float* __restrict__ b1,
                            const float* __restrict__ w2, float* __restrict__ ws)
{
    int t = threadIdx.x;
    unsigned short* a0 = (unsigned short*)ws;
    unsigned short* a1 = a0 + 2048;
    unsigned short* a2 = a1 + 4096;
    float* b0c = (float*)(a2 + 2048);
    float* b1c = b0c + 64;

    for (int e = t; e < 2048; e += 256) {
        int tile = e >> 9, lane = (e >> 3) & 63, j = e & 7;
        int m = tile >> 1, ks = tile & 1;
        int row = m * 32 + (lane & 31);
        int k = ks * 16 + (lane >> 5) * 8 + j;
        float v = (k < 26) ? w0[k * 64 + row] : 0.f;
        a0[e] = (unsigned short)f2bf(v);
    }
    for (int e = t; e < 4096; e += 256) {
        int tile = e >> 9, lane = (e >> 3) & 63, j = e & 7;
        int m = tile >> 2, ks = tile & 3;
        int row = m * 32 + (lane & 31);
        int k = ks * 16 + (lane >> 5) * 8 + j;
        a1[e] = (unsigned short)f2bf(w1[k * 64 + row]);
    }
    for (int e = t; e < 2048; e += 256) {
        int ks = e >> 9, lane = (e >> 3) & 63, j = e & 7;
        int row = lane & 31;
        int k = ks * 16 + (lane >> 5) * 8 + j;
        float v = (row < 4) ? w2[k * 4 + row] : 0.f;
        a2[e] = (unsigned short)f2bf(v);
    }
    if (t < 64) {
        int m = t >> 5, q5 = (t >> 4) & 1, r = t & 15;
        int row = (r & 3) + 8 * (r >> 2) + 4 * q5;
        b0c[(m * 2 + q5) * 16 + r] = b0[m * 32 + row];
        b1c[(m * 2 + q5) * 16 + r] = b1[m * 32 + row];
    }
}

// ---------- gather helper (unchanged, known-correct) ----------
template<int R>
__device__ __forceinline__ void gather_level(const float* __restrict__ g,
                                             float u, float v,
                                             float& e0, float& e1) {
    const float scale = (float)(R - 1);
    float fu = u * scale, fv = v * scale;
    int i0 = (int)floorf(fu);
    int j0 = (int)floorf(fv);
    i0 = i0 < 0 ? 0 : (i0 > R - 2 ? R - 2 : i0);
    j0 = j0 < 0 ? 0 : (j0 > R - 2 ? R - 2 : j0);
    float lu = fu - (float)i0;
    float lv = fv - (float)j0;
    const float2* gg = (const float2*)g;
    int base = i0 + j0 * R;
    float2 f00 = gg[base];
    float2 f10 = gg[base + 1];
    float2 f01 = gg[base + R];
    float2 f11 = gg[base + R + 1];
    float omu = 1.f - lu, omv = 1.f - lv;
    float w00 = omu * omv, w10 = lu * omv, w01 = omu * lv, w11 = lu * lv;
    e0 += f00.x * w00 + f10.x * w10 + f01.x * w01 + f11.x * w11;
    e1 += f00.y * w00 + f10.y * w10 + f01.y * w01 + f11.y * w11;
}

// ---------- main fused kernel: gather (per-lane) + LDS-free MFMA MLP ----------
__global__ __launch_bounds__(256, 4)
void colornet_mfma(const float* __restrict__ coords,
                   const float* __restrict__ g0, const float* __restrict__ g1,
                   const float* __restrict__ g2, const float* __restrict__ g3,
                   const float* __restrict__ g4, const float* __restrict__ g5,
                   const float* __restrict__ g6, const float* __restrict__ g7,
                   const float* __restrict__ lpe,
                   const float* __restrict__ ws,
                   const float* __restrict__ b2,
                   f32x4* __restrict__ out)
{
    const int lane = threadIdx.x & 63;
    const int wave = threadIdx.x >> 6;
    const int q5 = lane >> 5;
    const int base_pt = blockIdx.x * 256 + wave * 64;
    const int point = base_pt + lane;

    // ================= gather phase (per lane, one point) =================
    const float* cp = coords + 2 * point;
    float cx = __builtin_nontemporal_load(cp);
    float cy = __builtin_nontemporal_load(cp + 1);
    float u = fminf(fmaxf(cx, 0.f), 1.f - 1e-6f);
    float v = fminf(fmaxf(cy, 0.f), 1.f - 1e-6f);

    float e0 = 0.f, e1 = 0.f;
    gather_level<16>(g0, u, v, e0, e1);
    gather_level<32>(g1, u, v, e0, e1);
    gather_level<64>(g2, u, v, e0, e1);
    gather_level<128>(g3, u, v, e0, e1);
    gather_level<256>(g4, u, v, e0, e1);
    gather_level<512>(g5, u, v, e0, e1);
    gather_level<1024>(g6, u, v, e0, e1);
    gather_level<2048>(g7, u, v, e0, e1);

    float coeff[LPE_OUT];
    float lu_pe, lv_pe;
    {
        float fu = u * 128.f, fv = v * 128.f;
        int i0 = (int)floorf(fu);
        int j0 = (int)floorf(fv);
        i0 = i0 < 0 ? 0 : (i0 > 127 ? 127 : i0);
        j0 = j0 < 0 ? 0 : (j0 > 127 ? 127 : j0);
        lu_pe = fu - (float)i0;
        lv_pe = fv - (float)j0;
        int base = (i0 + j0 * 129) * LPE_OUT;
        const float4* p00 = (const float4*)(lpe + base);
        const float4* p10 = (const float4*)(lpe + base + LPE_OUT);
        const float4* p01 = (const float4*)(lpe + base + 129 * LPE_OUT);
        const float4* p11 = (const float4*)(lpe + base + 130 * LPE_OUT);
        float omu = 1.f - lu_pe, omv = 1.f - lv_pe;
        float w00 = omu * omv, w10 = lu_pe * omv, w01 = omu * lv_pe, w11 = lu_pe * lv_pe;
#pragma unroll
        for (int q = 0; q < 6; ++q) {
            float4 a = p00[q], bq = p10[q], cq = p01[q], dq = p11[q];
            coeff[4 * q + 0] = a.x * w00 + bq.x * w10 + cq.x * w01 + dq.x * w11;
            coeff[4 * q + 1] = a.y * w00 + bq.y * w10 + cq.y * w01 + dq.y * w11;
            coeff[4 * q + 2] = a.z * w00 + bq.z * w10 + cq.z * w01 + dq.z * w11;
            coeff[4 * q + 3] = a.w * w00 + bq.w * w10 + cq.w * w01 + dq.w * w11;
        }
    }

    float pe[4 * NF];
#pragma unroll
    for (int kf = 0; kf < NF; ++kf) {
        const float fr = 6.28318530717958647692f * (float)(1 << kf);
        float au = lu_pe * fr;
        float av = lv_pe * fr;
        pe[kf]          = __cosf(au);
        pe[NF + kf]     = __sinf(au);
        pe[2 * NF + kf] = __cosf(av);
        pe[3 * NF + kf] = __sinf(av);
    }

    float feat[32];
    feat[0] = e0;
    feat[1] = e1;
#pragma unroll
    for (int q = 0; q < D0; ++q) feat[2 + q] = coeff[q];
#pragma unroll
    for (int q = 0; q < 4 * NF; ++q) feat[2 + D0 + q] = coeff[D0 + q] * pe[q];
#pragma unroll
    for (int q = 26; q < 32; ++q) feat[q] = 0.f;

    // fd[i] = bf16 pack of (feat[2i], feat[2i+1]); lane owns its whole point
    unsigned fd[16];
#pragma unroll
    for (int i = 0; i < 16; ++i) fd[i] = pkbf(feat[2 * i], feat[2 * i + 1]);

    // ============ B0 fragments via permlane32_swap (no LDS) ============
    // word(ks,n,j2)[l] = feats k=16ks+8*(l>>5)+2j2+{0,1} of point (l&31)+32n
    unsigned B0[2][2][4];
#pragma unroll
    for (int ks = 0; ks < 2; ++ks)
#pragma unroll
        for (int j2 = 0; j2 < 4; ++j2) {
            unsigned a = fd[8 * ks + j2];        // k-lo half (q5_t=0 content)
            unsigned b = fd[8 * ks + 4 + j2];    // k-hi half (q5_t=1 content)
            auto r = __builtin_amdgcn_permlane32_swap(b, a, false, false);
            B0[ks][1][j2] = r[0];   // n=1: lo lanes pull partner's a, hi lanes own b
            B0[ks][0][j2] = r[1];   // n=0: lo lanes own a, hi lanes pull partner's b
        }

    const bf16x8* A0 = (const bf16x8*)ws;
    const bf16x8* A1 = (const bf16x8*)((const char*)ws + 4096);
    const bf16x8* A2 = (const bf16x8*)((const char*)ws + 12288);
    const float4* b0c = (const float4*)((const char*)ws + 16384);
    const float4* b1c = (const float4*)((const char*)ws + 16640);

    // ================= layer 0 (m-split) -> B1 frags =================
    unsigned B1[4][2][4];
#pragma unroll
    for (int m = 0; m < 2; ++m) {
        f32x16 acc[2];
#pragma unroll
        for (int cc = 0; cc < 4; ++cc) {
            float4 bq = b0c[(m * 2 + q5) * 4 + cc];
#pragma unroll
            for (int n = 0; n < 2; ++n) {
                acc[n][4 * cc + 0] = bq.x;
                acc[n][4 * cc + 1] = bq.y;
                acc[n][4 * cc + 2] = bq.z;
                acc[n][4 * cc + 3] = bq.w;
            }
        }
#pragma unroll
        for (int ks = 0; ks < 2; ++ks) {
            bf16x8 af = A0[(m * 2 + ks) * 64 + lane];
#pragma unroll
            for (int n = 0; n < 2; ++n)
                acc[n] = __builtin_amdgcn_mfma_f32_32x32x16_bf16(
                    af, mkfrag(B0[ks][n][0], B0[ks][n][1], B0[ks][n][2], B0[ks][n][3]),
                    acc[n], 0, 0, 0);
        }
        // pack h0 rows (with relu) into B1 words for ks2 = 2m+t
        // source regs: P_{q5_t}: r = 2c + 4*((2*ks2+q5_t)&3), m' = ks2>>1 == m
#pragma unroll
        for (int t = 0; t < 2; ++t) {
#pragma unroll
            for (int n = 0; n < 2; ++n)
#pragma unroll
                for (int c = 0; c < 2; ++c) {
                    int r0 = 2 * c + 8 * t;       // (2*(2m+t))&3 = 2t
                    int r1 = 2 * c + 8 * t + 4;   // (2*(2m+t)+1)&3 = 2t+1
                    unsigned P0 = pkbf(fmaxf(acc[n][r0], 0.f), fmaxf(acc[n][r0 + 1], 0.f));
                    unsigned P1 = pkbf(fmaxf(acc[n][r1], 0.f), fmaxf(acc[n][r1 + 1], 0.f));
                    auto r = __builtin_amdgcn_permlane32_swap(P1, P0, false, false);
                    B1[2 * m + t][n][c] = r[1];       // j2 = c   (low-half source)
                    B1[2 * m + t][n][2 + c] = r[0];   // j2 = 2+c (high-half source)
                }
        }
    }

    // ================= layer 1 (m-split) -> B2 frags =================
    unsigned B2[4][2][4];
#pragma unroll
    for (int m = 0; m < 2; ++m) {
        f32x16 acc[2];
#pragma unroll
        for (int cc = 0; cc < 4; ++cc) {
            float4 bq = b1c[(m * 2 + q5) * 4 + cc];
#pragma unroll
            for (int n = 0; n < 2; ++n) {
                acc[n][4 * cc + 0] = bq.x;
                acc[n][4 * cc + 1] = bq.y;
                acc[n][4 * cc + 2] = bq.z;
                acc[n][4 * cc + 3] = bq.w;
            }
        }
#pragma unroll
        for (int ks = 0; ks < 4; ++ks) {
            bf16x8 af = A1[(m * 4 + ks) * 64 + lane];
#pragma unroll
            for (int n = 0; n < 2; ++n)
                acc[n] = __builtin_amdgcn_mfma_f32_32x32x16_bf16(
                    af, mkfrag(B1[ks][n][0], B1[ks][n][1], B1[ks][n][2], B1[ks][n][3]),
                    acc[n], 0, 0, 0);
        }
#pragma unroll
        for (int t = 0; t < 2; ++t) {
#pragma unroll
            for (int n = 0; n < 2; ++n)
#pragma unroll
                for (int c = 0; c < 2; ++c) {
                    int r0 = 2 * c + 8 * t;
                    int r1 = 2 * c + 8 * t + 4;
                    unsigned P0 = pkbf(fmaxf(acc[n][r0], 0.f), fmaxf(acc[n][r0 + 1], 0.f));
                    unsigned P1 = pkbf(fmaxf(acc[n][r1], 0.f), fmaxf(acc[n][r1 + 1], 0.f));
                    auto r = __builtin_amdgcn_permlane32_swap(P1, P0, false, false);
                    B2[2 * m + t][n][c] = r[1];
                    B2[2 * m + t][n][2 + c] = r[0];
                }
        }
    }

    // ================= layer 2: rows 0..3 real, K=64 =================
    f32x16 acc2[2];
#pragma unroll
    for (int n = 0; n < 2; ++n)
#pragma unroll
        for (int r = 0; r < 16; ++r) acc2[n][r] = (r < 4) ? b2[r] : 0.f;
#pragma unroll
    for (int ks = 0; ks < 4; ++ks) {
        bf16x8 af = A2[ks * 64 + lane];
#pragma unroll
        for (int n = 0; n < 2; ++n)
            acc2[n] = __builtin_amdgcn_mfma_f32_32x32x16_bf16(
                af, mkfrag(B2[ks][n][0], B2[ks][n][1], B2[ks][n][2], B2[ks][n][3]),
                acc2[n], 0, 0, 0);
    }

    // sigmoid + store: lanes 0..31 (q5==0) hold rows t=0..3
    if (lane < 32) {
#pragma unroll
        for (int n = 0; n < 2; ++n) {
            f32x4 o;
            o[0] = 1.f / (1.f + __expf(-acc2[n][0]));
            o[1] = 1.f / (1.f + __expf(-acc2[n][1]));
            o[2] = 1.f / (1.f + __expf(-acc2[n][2]));
            o[3] = 1.f / (1.f + __expf(-acc2[n][3]));
            __builtin_nontemporal_store(o, out + (base_pt + 32 * n + lane));
        }
    }
}

extern "C" void kernel_launch(void* const* d_in, const int* in_sizes, int n_in,
                              void* d_out, int out_size, void* d_ws, size_t ws_size,
                              hipStream_t stream) {
    const float* coords = (const float*)d_in[0];
    const float* g0 = (const float*)d_in[1];
    const float* g1 = (const float*)d_in[2];
    const float* g2 = (const float*)d_in[3];
    const float* g3 = (const float*)d_in[4];
    const float* g4 = (const float*)d_in[5];
    const float* g5 = (const float*)d_in[6];
    const float* g6 = (const float*)d_in[7];
    const float* g7 = (const float*)d_in[8];
    const float* lpe = (const float*)d_in[9];
    const float* w0 = (const float*)d_in[10];
    const float* b0 = (const float*)d_in[11];
    const float* w1 = (const float*)d_in[12];
    const float* b1 = (const float*)d_in[13];
    const float* w2 = (const float*)d_in[14];
    const float* b2 = (const float*)d_in[15];
    f32x4* out = (f32x4*)d_out;

    int B = in_sizes[0] / 2;

    prep_kernel<<<1, 256, 0, stream>>>(w0, b0, w1, b1, w2, (float*)d_ws);

    int grid = B / 256;   // B = 1048576 -> 4096 blocks, exact
    colornet_mfma<<<grid, 256, 0, stream>>>(coords, g0, g1, g2, g3, g4, g5, g6, g7,
                                            lpe, (const float*)d_ws, b2, out);
}

// Round 5
// 183.693 us; speedup vs baseline: 1.8412x; 1.0625x over previous
//
#include <hip/hip_runtime.h>
#include <math.h>

typedef short bf16x8 __attribute__((ext_vector_type(8)));
typedef float f32x16 __attribute__((ext_vector_type(16)));
typedef float f32x4 __attribute__((ext_vector_type(4)));
typedef unsigned u32x4 __attribute__((ext_vector_type(4)));

#define NF 4
#define D0 8
#define LPE_OUT 24

// ---------------- ws byte layout ----------------
// [0,16896)            A-frags + C-layout biases (prep_kernel)
// [17408, +798768)     LPE bf16: cell*12 u32 (48B/cell), 16641 cells
// G*_OFF               bf16 grids: cell = u32 (lo=ch0, hi=ch1)
#define LPE_OFF   17408
#define G0_OFF    816384
#define G1_OFF    817408
#define G2_OFF    821504
#define G3_OFF    837888
#define G4_OFF    903424
#define G5_OFF    1165568
#define G6_OFF    2214144
#define G7_OFF    6408448
#define WS_NEED   23185664ULL

// ---------- bf16 helpers ----------
__device__ __forceinline__ unsigned f2bf(float x) {
    unsigned u = __float_as_uint(x);
    u = u + 0x7fffu + ((u >> 16) & 1u);
    return u >> 16;
}
__device__ __forceinline__ unsigned pkbf(float a, float b) {
    return f2bf(a) | (f2bf(b) << 16);
}
__device__ __forceinline__ float bflo(unsigned u) { return __uint_as_float(u << 16); }
__device__ __forceinline__ float bfhi(unsigned u) { return __uint_as_float(u & 0xffff0000u); }
__device__ __forceinline__ bf16x8 mkfrag(unsigned w0, unsigned w1, unsigned w2, unsigned w3) {
    u32x4 u = { w0, w1, w2, w3 };
    return __builtin_bit_cast(bf16x8, u);
}

// ---------- weight prep (R3/R4-verified, unchanged) ----------
__global__ void prep_kernel(const float* __restrict__ w0, const float* __restrict__ b0,
                            const float* __restrict__ w1, const float* __restrict__ b1,
                            const float* __restrict__ w2, float* __restrict__ ws)
{
    int t = threadIdx.x;
    unsigned short* a0 = (unsigned short*)ws;
    unsigned short* a1 = a0 + 2048;
    unsigned short* a2 = a1 + 4096;
    float* b0c = (float*)(a2 + 2048);
    float* b1c = b0c + 64;

    for (int e = t; e < 2048; e += 256) {
        int tile = e >> 9, lane = (e >> 3) & 63, j = e & 7;
        int m = tile >> 1, ks = tile & 1;
        int row = m * 32 + (lane & 31);
        int k = ks * 16 + (lane >> 5) * 8 + j;
        float v = (k < 26) ? w0[k * 64 + row] : 0.f;
        a0[e] = (unsigned short)f2bf(v);
    }
    for (int e = t; e < 4096; e += 256) {
        int tile = e >> 9, lane = (e >> 3) & 63, j = e & 7;
        int m = tile >> 2, ks = tile & 3;
        int row = m * 32 + (lane & 31);
        int k = ks * 16 + (lane >> 5) * 8 + j;
        a1[e] = (unsigned short)f2bf(w1[k * 64 + row]);
    }
    for (int e = t; e < 2048; e += 256) {
        int ks = e >> 9, lane = (e >> 3) & 63, j = e & 7;
        int row = lane & 31;
        int k = ks * 16 + (lane >> 5) * 8 + j;
        float v = (row < 4) ? w2[k * 4 + row] : 0.f;
        a2[e] = (unsigned short)f2bf(v);
    }
    if (t < 64) {
        int m = t >> 5, q5 = (t >> 4) & 1, r = t & 15;
        int row = (r & 3) + 8 * (r >> 2) + 4 * q5;
        b0c[(m * 2 + q5) * 16 + r] = b0[m * 32 + row];
        b1c[(m * 2 + q5) * 16 + r] = b1[m * 32 + row];
    }
}

// ---------- grid fp32->bf16 conversion (all 8 levels, one kernel) ----------
__global__ void conv_grids(const float2* __restrict__ g0, const float2* __restrict__ g1,
                           const float2* __restrict__ g2, const float2* __restrict__ g3,
                           const float2* __restrict__ g4, const float2* __restrict__ g5,
                           const float2* __restrict__ g6, const float2* __restrict__ g7,
                           char* __restrict__ wsb)
{
    int b = blockIdx.x, t = threadIdx.x;
    const float2* s; unsigned* d; int cell;
    if (b < 16384)      { s = g7; d = (unsigned*)(wsb + G7_OFF); cell = b * 256 + t; }
    else if (b < 20480) { s = g6; d = (unsigned*)(wsb + G6_OFF); cell = (b - 16384) * 256 + t; }
    else if (b < 21504) { s = g5; d = (unsigned*)(wsb + G5_OFF); cell = (b - 20480) * 256 + t; }
    else if (b < 21760) { s = g4; d = (unsigned*)(wsb + G4_OFF); cell = (b - 21504) * 256 + t; }
    else if (b < 21824) { s = g3; d = (unsigned*)(wsb + G3_OFF); cell = (b - 21760) * 256 + t; }
    else if (b < 21840) { s = g2; d = (unsigned*)(wsb + G2_OFF); cell = (b - 21824) * 256 + t; }
    else if (b < 21844) { s = g1; d = (unsigned*)(wsb + G1_OFF); cell = (b - 21840) * 256 + t; }
    else                { s = g0; d = (unsigned*)(wsb + G0_OFF); cell = t; }
    float2 f = s[cell];
    d[cell] = pkbf(f.x, f.y);
}

// ---------- LPE fp32->bf16: cell = 12 u32 words (3 x u32x4) ----------
__global__ void conv_lpe(const float4* __restrict__ src, u32x4* __restrict__ dst)
{
    int t = blockIdx.x * 256 + threadIdx.x;   // t < 16641*3 = 49923
    if (t < 49923) {
        float4 a = src[t * 2], b = src[t * 2 + 1];
        u32x4 o = { pkbf(a.x, a.y), pkbf(a.z, a.w), pkbf(b.x, b.y), pkbf(b.z, b.w) };
        dst[t] = o;
    }
}

// ---------- fp32 gather (R4-verified, for fallback path) ----------
template<int R>
__device__ __forceinline__ void gather_level(const float* __restrict__ g,
                                             float u, float v,
                                             float& e0, float& e1) {
    const float scale = (float)(R - 1);
    float fu = u * scale, fv = v * scale;
    int i0 = (int)floorf(fu);
    int j0 = (int)floorf(fv);
    i0 = i0 < 0 ? 0 : (i0 > R - 2 ? R - 2 : i0);
    j0 = j0 < 0 ? 0 : (j0 > R - 2 ? R - 2 : j0);
    float lu = fu - (float)i0;
    float lv = fv - (float)j0;
    const float2* gg = (const float2*)g;
    int base = i0 + j0 * R;
    float2 f00 = gg[base];
    float2 f10 = gg[base + 1];
    float2 f01 = gg[base + R];
    float2 f11 = gg[base + R + 1];
    float omu = 1.f - lu, omv = 1.f - lv;
    float w00 = omu * omv, w10 = lu * omv, w01 = omu * lv, w11 = lu * lv;
    e0 += f00.x * w00 + f10.x * w10 + f01.x * w01 + f11.x * w11;
    e1 += f00.y * w00 + f10.y * w10 + f01.y * w01 + f11.y * w11;
}

// level addr/load/consume macros (bf16 path, two-phase)
#define LEVEL_ADDR(IDX, R) int b##IDX; float lu##IDX, lv##IDX; \
    { float fu_ = u * (float)((R) - 1), fv_ = v * (float)((R) - 1); \
      int i0_ = (int)floorf(fu_), j0_ = (int)floorf(fv_); \
      i0_ = i0_ < 0 ? 0 : (i0_ > (R) - 2 ? (R) - 2 : i0_); \
      j0_ = j0_ < 0 ? 0 : (j0_ > (R) - 2 ? (R) - 2 : j0_); \
      lu##IDX = fu_ - (float)i0_; lv##IDX = fv_ - (float)j0_; \
      b##IDX = i0_ + j0_ * (R); }

#define LEVEL_LOAD(IDX, R, OFF) \
    const unsigned* G##IDX = (const unsigned*)(wsb + (OFF)); \
    unsigned t##IDX##_0 = G##IDX[b##IDX],       t##IDX##_1 = G##IDX[b##IDX + 1], \
             t##IDX##_2 = G##IDX[b##IDX + (R)], t##IDX##_3 = G##IDX[b##IDX + (R) + 1];

#define LEVEL_SUM(IDX) { \
    float omu_ = 1.f - lu##IDX, omv_ = 1.f - lv##IDX; \
    float w00_ = omu_ * omv_, w10_ = lu##IDX * omv_, w01_ = omu_ * lv##IDX, w11_ = lu##IDX * lv##IDX; \
    e0 += bflo(t##IDX##_0) * w00_ + bflo(t##IDX##_1) * w10_ + bflo(t##IDX##_2) * w01_ + bflo(t##IDX##_3) * w11_; \
    e1 += bfhi(t##IDX##_0) * w00_ + bfhi(t##IDX##_1) * w10_ + bfhi(t##IDX##_2) * w01_ + bfhi(t##IDX##_3) * w11_; }

// ---------- main fused kernel ----------
template<bool BF>
__global__ __launch_bounds__(256, 4)
void colornet_mfma(const float* __restrict__ coords,
                   const float* __restrict__ g0, const float* __restrict__ g1,
                   const float* __restrict__ g2, const float* __restrict__ g3,
                   const float* __restrict__ g4, const float* __restrict__ g5,
                   const float* __restrict__ g6, const float* __restrict__ g7,
                   const float* __restrict__ lpe,
                   const float* __restrict__ ws,
                   const float* __restrict__ b2,
                   f32x4* __restrict__ out)
{
    const int lane = threadIdx.x & 63;
    const int wave = threadIdx.x >> 6;
    const int q5 = lane >> 5;
    const int base_pt = blockIdx.x * 256 + wave * 64;
    const int point = base_pt + lane;
    const char* wsb = (const char*)ws;

    const float* cp = coords + 2 * point;
    float cx = __builtin_nontemporal_load(cp);
    float cy = __builtin_nontemporal_load(cp + 1);
    float u = fminf(fmaxf(cx, 0.f), 1.f - 1e-6f);
    float v = fminf(fmaxf(cy, 0.f), 1.f - 1e-6f);

    float e0 = 0.f, e1 = 0.f;
    float coeff[LPE_OUT];
    float lu_pe, lv_pe;
    float pe[4 * NF];

    if constexpr (BF) {
        // -------- phase A: all addresses, then all loads (far first) --------
        LEVEL_ADDR(7, 2048) LEVEL_ADDR(6, 1024) LEVEL_ADDR(5, 512) LEVEL_ADDR(4, 256)
        LEVEL_ADDR(3, 128)  LEVEL_ADDR(2, 64)   LEVEL_ADDR(1, 32)  LEVEL_ADDR(0, 16)

        LEVEL_LOAD(7, 2048, G7_OFF)
        LEVEL_LOAD(6, 1024, G6_OFF)
        LEVEL_LOAD(5, 512,  G5_OFF)
        LEVEL_LOAD(4, 256,  G4_OFF)
        LEVEL_LOAD(3, 128,  G3_OFF)
        LEVEL_LOAD(2, 64,   G2_OFF)
        LEVEL_LOAD(1, 32,   G1_OFF)
        LEVEL_LOAD(0, 16,   G0_OFF)

        // LPE addresses + 12 dwordx4 loads
        {
            float fu = u * 128.f, fv = v * 128.f;
            int i0 = (int)floorf(fu);
            int j0 = (int)floorf(fv);
            i0 = i0 < 0 ? 0 : (i0 > 127 ? 127 : i0);
            j0 = j0 < 0 ? 0 : (j0 > 127 ? 127 : j0);
            lu_pe = fu - (float)i0;
            lv_pe = fv - (float)j0;
            int lc = (i0 + j0 * 129) * 3;
            const u32x4* LP = (const u32x4*)(wsb + LPE_OFF);
            u32x4 L00a = LP[lc],       L00b = LP[lc + 1],   L00c = LP[lc + 2];
            u32x4 L10a = LP[lc + 3],   L10b = LP[lc + 4],   L10c = LP[lc + 5];
            u32x4 L01a = LP[lc + 387], L01b = LP[lc + 388], L01c = LP[lc + 389];
            u32x4 L11a = LP[lc + 390], L11b = LP[lc + 391], L11c = LP[lc + 392];

            // -------- compute trig while loads fly --------
#pragma unroll
            for (int kf = 0; kf < NF; ++kf) {
                const float fr = 6.28318530717958647692f * (float)(1 << kf);
                float au = lu_pe * fr;
                float av = lv_pe * fr;
                pe[kf]          = __cosf(au);
                pe[NF + kf]     = __sinf(au);
                pe[2 * NF + kf] = __cosf(av);
                pe[3 * NF + kf] = __sinf(av);
            }

            // -------- phase B: consume in issue order --------
            LEVEL_SUM(7) LEVEL_SUM(6) LEVEL_SUM(5) LEVEL_SUM(4)
            LEVEL_SUM(3) LEVEL_SUM(2) LEVEL_SUM(1) LEVEL_SUM(0)

            float omu = 1.f - lu_pe, omv = 1.f - lv_pe;
            float q00 = omu * omv, q10 = lu_pe * omv, q01 = omu * lv_pe, q11 = lu_pe * lv_pe;
#define LPW(W, A, B, C, Dd) \
            coeff[2*(W)]   = bflo(A)*q00 + bflo(B)*q10 + bflo(C)*q01 + bflo(Dd)*q11; \
            coeff[2*(W)+1] = bfhi(A)*q00 + bfhi(B)*q10 + bfhi(C)*q01 + bfhi(Dd)*q11;
            LPW(0,  L00a[0], L10a[0], L01a[0], L11a[0])
            LPW(1,  L00a[1], L10a[1], L01a[1], L11a[1])
            LPW(2,  L00a[2], L10a[2], L01a[2], L11a[2])
            LPW(3,  L00a[3], L10a[3], L01a[3], L11a[3])
            LPW(4,  L00b[0], L10b[0], L01b[0], L11b[0])
            LPW(5,  L00b[1], L10b[1], L01b[1], L11b[1])
            LPW(6,  L00b[2], L10b[2], L01b[2], L11b[2])
            LPW(7,  L00b[3], L10b[3], L01b[3], L11b[3])
            LPW(8,  L00c[0], L10c[0], L01c[0], L11c[0])
            LPW(9,  L00c[1], L10c[1], L01c[1], L11c[1])
            LPW(10, L00c[2], L10c[2], L01c[2], L11c[2])
            LPW(11, L00c[3], L10c[3], L01c[3], L11c[3])
#undef LPW
        }
    } else {
        // -------- R4-verified fp32 fallback --------
        gather_level<16>(g0, u, v, e0, e1);
        gather_level<32>(g1, u, v, e0, e1);
        gather_level<64>(g2, u, v, e0, e1);
        gather_level<128>(g3, u, v, e0, e1);
        gather_level<256>(g4, u, v, e0, e1);
        gather_level<512>(g5, u, v, e0, e1);
        gather_level<1024>(g6, u, v, e0, e1);
        gather_level<2048>(g7, u, v, e0, e1);
        {
            float fu = u * 128.f, fv = v * 128.f;
            int i0 = (int)floorf(fu);
            int j0 = (int)floorf(fv);
            i0 = i0 < 0 ? 0 : (i0 > 127 ? 127 : i0);
            j0 = j0 < 0 ? 0 : (j0 > 127 ? 127 : j0);
            lu_pe = fu - (float)i0;
            lv_pe = fv - (float)j0;
            int base = (i0 + j0 * 129) * LPE_OUT;
            const float4* p00 = (const float4*)(lpe + base);
            const float4* p10 = (const float4*)(lpe + base + LPE_OUT);
            const float4* p01 = (const float4*)(lpe + base + 129 * LPE_OUT);
            const float4* p11 = (const float4*)(lpe + base + 130 * LPE_OUT);
            float omu = 1.f - lu_pe, omv = 1.f - lv_pe;
            float w00 = omu * omv, w10 = lu_pe * omv, w01 = omu * lv_pe, w11 = lu_pe * lv_pe;
#pragma unroll
            for (int q = 0; q < 6; ++q) {
                float4 a = p00[q], bq = p10[q], cq = p01[q], dq = p11[q];
                coeff[4 * q + 0] = a.x * w00 + bq.x * w10 + cq.x * w01 + dq.x * w11;
                coeff[4 * q + 1] = a.y * w00 + bq.y * w10 + cq.y * w01 + dq.y * w11;
                coeff[4 * q + 2] = a.z * w00 + bq.z * w10 + cq.z * w01 + dq.z * w11;
                coeff[4 * q + 3] = a.w * w00 + bq.w * w10 + cq.w * w01 + dq.w * w11;
            }
        }
#pragma unroll
        for (int kf = 0; kf < NF; ++kf) {
            const float fr = 6.28318530717958647692f * (float)(1 << kf);
            float au = lu_pe * fr;
            float av = lv_pe * fr;
            pe[kf]          = __cosf(au);
            pe[NF + kf]     = __sinf(au);
            pe[2 * NF + kf] = __cosf(av);
            pe[3 * NF + kf] = __sinf(av);
        }
    }

    // ---- feature vector + bf16 pack (lane owns its point) ----
    float feat[32];
    feat[0] = e0;
    feat[1] = e1;
#pragma unroll
    for (int q = 0; q < D0; ++q) feat[2 + q] = coeff[q];
#pragma unroll
    for (int q = 0; q < 4 * NF; ++q) feat[2 + D0 + q] = coeff[D0 + q] * pe[q];
#pragma unroll
    for (int q = 26; q < 32; ++q) feat[q] = 0.f;

    unsigned fd[16];
#pragma unroll
    for (int i = 0; i < 16; ++i) fd[i] = pkbf(feat[2 * i], feat[2 * i + 1]);

    // ============ B0 fragments via permlane32_swap (R4-verified) ============
    unsigned B0[2][2][4];
#pragma unroll
    for (int ks = 0; ks < 2; ++ks)
#pragma unroll
        for (int j2 = 0; j2 < 4; ++j2) {
            unsigned a = fd[8 * ks + j2];
            unsigned b = fd[8 * ks + 4 + j2];
            auto r = __builtin_amdgcn_permlane32_swap(b, a, false, false);
            B0[ks][1][j2] = r[0];
            B0[ks][0][j2] = r[1];
        }

    const bf16x8* A0 = (const bf16x8*)ws;
    const bf16x8* A1 = (const bf16x8*)((const char*)ws + 4096);
    const bf16x8* A2 = (const bf16x8*)((const char*)ws + 12288);
    const float4* b0c = (const float4*)((const char*)ws + 16384);
    const float4* b1c = (const float4*)((const char*)ws + 16640);

    // ================= layer 0 (m-split) -> B1 frags =================
    unsigned B1[4][2][4];
#pragma unroll
    for (int m = 0; m < 2; ++m) {
        f32x16 acc[2];
#pragma unroll
        for (int cc = 0; cc < 4; ++cc) {
            float4 bq = b0c[(m * 2 + q5) * 4 + cc];
#pragma unroll
            for (int n = 0; n < 2; ++n) {
                acc[n][4 * cc + 0] = bq.x;
                acc[n][4 * cc + 1] = bq.y;
                acc[n][4 * cc + 2] = bq.z;
                acc[n][4 * cc + 3] = bq.w;
            }
        }
#pragma unroll
        for (int ks = 0; ks < 2; ++ks) {
            bf16x8 af = A0[(m * 2 + ks) * 64 + lane];
#pragma unroll
            for (int n = 0; n < 2; ++n)
                acc[n] = __builtin_amdgcn_mfma_f32_32x32x16_bf16(
                    af, mkfrag(B0[ks][n][0], B0[ks][n][1], B0[ks][n][2], B0[ks][n][3]),
                    acc[n], 0, 0, 0);
        }
#pragma unroll
        for (int t = 0; t < 2; ++t) {
#pragma unroll
            for (int n = 0; n < 2; ++n)
#pragma unroll
                for (int c = 0; c < 2; ++c) {
                    int r0 = 2 * c + 8 * t;
                    int r1 = 2 * c + 8 * t + 4;
                    unsigned P0 = pkbf(fmaxf(acc[n][r0], 0.f), fmaxf(acc[n][r0 + 1], 0.f));
                    unsigned P1 = pkbf(fmaxf(acc[n][r1], 0.f), fmaxf(acc[n][r1 + 1], 0.f));
                    auto r = __builtin_amdgcn_permlane32_swap(P1, P0, false, false);
                    B1[2 * m + t][n][c] = r[1];
                    B1[2 * m + t][n][2 + c] = r[0];
                }
        }
    }

    // ================= layer 1 (m-split) -> B2 frags =================
    unsigned B2[4][2][4];
#pragma unroll
    for (int m = 0; m < 2; ++m) {
        f32x16 acc[2];
#pragma unroll
        for (int cc = 0; cc < 4; ++cc) {
            float4 bq = b1c[(m * 2 + q5) * 4 + cc];
#pragma unroll
            for (int n = 0; n < 2; ++n) {
                acc[n][4 * cc + 0] = bq.x;
                acc[n][4 * cc + 1] = bq.y;
                acc[n][4 * cc + 2] = bq.z;
                acc[n][4 * cc + 3] = bq.w;
            }
        }
#pragma unroll
        for (int ks = 0; ks < 4; ++ks) {
            bf16x8 af = A1[(m * 4 + ks) * 64 + lane];
#pragma unroll
            for (int n = 0; n < 2; ++n)
                acc[n] = __builtin_amdgcn_mfma_f32_32x32x16_bf16(
                    af, mkfrag(B1[ks][n][0], B1[ks][n][1], B1[ks][n][2], B1[ks][n][3]),
                    acc[n], 0, 0, 0);
        }
#pragma unroll
        for (int t = 0; t < 2; ++t) {
#pragma unroll
            for (int n = 0; n < 2; ++n)
#pragma unroll
                for (int c = 0; c < 2; ++c) {
                    int r0 = 2 * c + 8 * t;
                    int r1 = 2 * c + 8 * t + 4;
                    unsigned P0 = pkbf(fmaxf(acc[n][r0], 0.f), fmaxf(acc[n][r0 + 1], 0.f));
                    unsigned P1 = pkbf(fmaxf(acc[n][r1], 0.f), fmaxf(acc[n][r1 + 1], 0.f));
                    auto r = __builtin_amdgcn_permlane32_swap(P1, P0, false, false);
                    B2[2 * m + t][n][c] = r[1];
                    B2[2 * m + t][n][2 + c] = r[0];
                }
        }
    }

    // ================= layer 2 =================
    f32x16 acc2[2];
#pragma unroll
    for (int n = 0; n < 2; ++n)
#pragma unroll
        for (int r = 0; r < 16; ++r) acc2[n][r] = (r < 4) ? b2[r] : 0.f;
#pragma unroll
    for (int ks = 0; ks < 4; ++ks) {
        bf16x8 af = A2[ks * 64 + lane];
#pragma unroll
        for (int n = 0; n < 2; ++n)
            acc2[n] = __builtin_amdgcn_mfma_f32_32x32x16_bf16(
                af, mkfrag(B2[ks][n][0], B2[ks][n][1], B2[ks][n][2], B2[ks][n][3]),
                acc2[n], 0, 0, 0);
    }

    if (lane < 32) {
#pragma unroll
        for (int n = 0; n < 2; ++n) {
            f32x4 o;
            o[0] = 1.f / (1.f + __expf(-acc2[n][0]));
            o[1] = 1.f / (1.f + __expf(-acc2[n][1]));
            o[2] = 1.f / (1.f + __expf(-acc2[n][2]));
            o[3] = 1.f / (1.f + __expf(-acc2[n][3]));
            __builtin_nontemporal_store(o, out + (base_pt + 32 * n + lane));
        }
    }
}

extern "C" void kernel_launch(void* const* d_in, const int* in_sizes, int n_in,
                              void* d_out, int out_size, void* d_ws, size_t ws_size,
                              hipStream_t stream) {
    const float* coords = (const float*)d_in[0];
    const float* g0 = (const float*)d_in[1];
    const float* g1 = (const float*)d_in[2];
    const float* g2 = (const float*)d_in[3];
    const float* g3 = (const float*)d_in[4];
    const float* g4 = (const float*)d_in[5];
    const float* g5 = (const float*)d_in[6];
    const float* g6 = (const float*)d_in[7];
    const float* g7 = (const float*)d_in[8];
    const float* lpe = (const float*)d_in[9];
    const float* w0 = (const float*)d_in[10];
    const float* b0 = (const float*)d_in[11];
    const float* w1 = (const float*)d_in[12];
    const float* b1 = (const float*)d_in[13];
    const float* w2 = (const float*)d_in[14];
    const float* b2 = (const float*)d_in[15];
    f32x4* out = (f32x4*)d_out;

    int B = in_sizes[0] / 2;
    int grid = B / 256;   // B = 1048576 -> 4096 blocks

    prep_kernel<<<1, 256, 0, stream>>>(w0, b0, w1, b1, w2, (float*)d_ws);

    if (ws_size >= WS_NEED) {
        conv_grids<<<21845, 256, 0, stream>>>((const float2*)g0, (const float2*)g1,
                                              (const float2*)g2, (const float2*)g3,
                                              (const float2*)g4, (const float2*)g5,
                                              (const float2*)g6, (const float2*)g7,
                                              (char*)d_ws);
        conv_lpe<<<196, 256, 0, stream>>>((const float4*)lpe,
                                          (u32x4*)((char*)d_ws + LPE_OFF));
        colornet_mfma<true><<<grid, 256, 0, stream>>>(coords, g0, g1, g2, g3, g4, g5, g6, g7,
                                                      lpe, (const float*)d_ws, b2, out);
    } else {
        colornet_mfma<false><<<grid, 256, 0, stream>>>(coords, g0, g1, g2, g3, g4, g5, g6, g7,
                                                       lpe, (const float*)d_ws, b2, out);
    }
}